// Round 15
// baseline (87.045 us; speedup 1.0000x reference)
//
#include <hip/hip_runtime.h>
#include <math.h>

#define NS 512
#define DE 512
#define NCL 5
#define NBLK 256

// ws layout: dots[512*512] | dg[512] | psum[256] | pnz[256] | ticket[1]
// ticket zeroed by k_dots block(0,0) (stream-ordered before k_loss).

// ---------------------------------------------------------------------------
// K1: dot tiles (R12-proven). Grid (32 ag, 8 jq), 512 threads. Block =
//     anchors a0..a0+16 x rows j0..j0+64. 16-lane group owns 2 j-rows;
//     per k-chunk loads 16 anchor f4 frags + 2 row f4s, 136 FMA.
//     Butterfly-reduce, LDS bounce, coalesced writes. Self-dots -> dg.
// ---------------------------------------------------------------------------
__global__ __launch_bounds__(512, 2) void k_dots(const float* __restrict__ pred,
                                                 float* __restrict__ dots,
                                                 float* __restrict__ dg,
                                                 unsigned int* __restrict__ ticket) {
    const int a0 = blockIdx.x * 16;
    const int j0 = blockIdx.y * 64;
    const int tid = threadIdx.x;
    if (blockIdx.x == 0 && blockIdx.y == 0 && tid == 0) *ticket = 0u;

    const int w = tid >> 6, lane = tid & 63;
    const int g = lane >> 4, s = lane & 15;
    const int jl0 = (w * 4 + g) * 2;

    __shared__ float tile[16][65];
    __shared__ float stile[64];

    const float4* p4 = (const float4*)pred;
    const float4* pj0 = p4 + (size_t)(j0 + jl0) * (DE / 4);
    const float4* pj1 = p4 + (size_t)(j0 + jl0 + 1) * (DE / 4);

    float acc0[17] = {};
    float acc1[17] = {};

#pragma unroll 2
    for (int kb = 0; kb < 8; kb++) {
        float4 fa[16];
#pragma unroll
        for (int a = 0; a < 16; a++)
            fa[a] = p4[(size_t)(a0 + a) * (DE / 4) + kb * 16 + s];
        float4 x0 = pj0[kb * 16 + s];
        float4 x1 = pj1[kb * 16 + s];
#pragma unroll
        for (int a = 0; a < 16; a++) {
            acc0[a] = fmaf(x0.x, fa[a].x, acc0[a]); acc0[a] = fmaf(x0.y, fa[a].y, acc0[a]);
            acc0[a] = fmaf(x0.z, fa[a].z, acc0[a]); acc0[a] = fmaf(x0.w, fa[a].w, acc0[a]);
            acc1[a] = fmaf(x1.x, fa[a].x, acc1[a]); acc1[a] = fmaf(x1.y, fa[a].y, acc1[a]);
            acc1[a] = fmaf(x1.z, fa[a].z, acc1[a]); acc1[a] = fmaf(x1.w, fa[a].w, acc1[a]);
        }
        acc0[16] = fmaf(x0.x, x0.x, acc0[16]); acc0[16] = fmaf(x0.y, x0.y, acc0[16]);
        acc0[16] = fmaf(x0.z, x0.z, acc0[16]); acc0[16] = fmaf(x0.w, x0.w, acc0[16]);
        acc1[16] = fmaf(x1.x, x1.x, acc1[16]); acc1[16] = fmaf(x1.y, x1.y, acc1[16]);
        acc1[16] = fmaf(x1.z, x1.z, acc1[16]); acc1[16] = fmaf(x1.w, x1.w, acc1[16]);
    }

#pragma unroll
    for (int m = 1; m <= 8; m <<= 1) {
#pragma unroll
        for (int a = 0; a < 17; a++) {
            acc0[a] += __shfl_xor(acc0[a], m);
            acc1[a] += __shfl_xor(acc1[a], m);
        }
    }

    tile[s][jl0]     = acc0[s];
    tile[s][jl0 + 1] = acc1[s];
    if (s == 0) { stile[jl0] = acc0[16]; stile[jl0 + 1] = acc1[16]; }
    __syncthreads();

#pragma unroll
    for (int r = 0; r < 2; r++) {
        int idx = tid + r * 512;
        int a = idx >> 6, jl = idx & 63;
        dots[(size_t)(a0 + a) * NS + j0 + jl] = tile[a][jl];
    }
    if (tid < 64) dg[j0 + tid] = stile[tid];
}

// ---------------------------------------------------------------------------
// K2: loss for anchors iA=b, iB=b+256 (R14 body, shuffle reductions) +
//     ticket finalize: partials to distinct lines (plain stores), one
//     fire-and-forget ticket RMW, last block parallel-reads partials
//     with agent-scope atomic loads and writes out.
// ---------------------------------------------------------------------------
__global__ __launch_bounds__(512) void k_loss(const float* __restrict__ dots,
                                              const float* __restrict__ dg,
                                              const int* __restrict__ target,
                                              const float* __restrict__ draw,
                                              float* __restrict__ psum,
                                              int* __restrict__ pnz,
                                              unsigned int* __restrict__ ticket,
                                              float* __restrict__ out) {
    const int b = blockIdx.x;
    const int tid = threadIdx.x;
    const int iA = b, iB = b + 256;

    __shared__ float  rn_s[NS];
    __shared__ float  ckA[NS], ckB[NS];
    __shared__ float4 v4sA[NS / 4], v4sB[NS / 4];
    __shared__ int    pkA[NS], pkB[NS];
    __shared__ float  spart[NS * 17];
    __shared__ float  wf[8];
    __shared__ int    wi[8];
    __shared__ unsigned int pcA, pcB, last_flag;

    if (tid == 0) { pcA = 0u; pcB = 0u; }

    const int j = tid;
    const float da = dots[(size_t)iA * NS + j];
    const float db = dots[(size_t)iB * NS + j];
    const float rnj = 1.0f / fmaxf(sqrtf(dg[j]), 1e-8f);
    rn_s[j] = rnj;

    float cp[NCL];
    cp[0] = 0.0f;
#pragma unroll
    for (int c = 0; c < NCL - 1; c++) cp[c + 1] = cp[c] + log1pf(expf(draw[c]));
    const int tiA = target[iA], tiB = target[iB];
    const float cpA = cp[tiA], cpB = cp[tiB];
    const int tj = target[j];
    const float cpj = cp[tj];
    __syncthreads();

    const float rniA = rn_s[iA], rniB = rn_s[iB];
    int nc;
    {   // anchor A
        float c0 = da * rniA * rnj;
        bool n0 = (tj != tiA);
        ckA[j] = c0;
        ((float*)v4sA)[j] = n0 ? (c0 + fabsf(cpA - cpj)) : -1e30f;
        if (!n0 && j != iA) pkA[atomicAdd(&pcA, 1u)] = j;
        nc = (n0 ? 1 : 0);
    }
    {   // anchor B (packed: A low 16, B high 16)
        float c0 = db * rniB * rnj;
        bool n0 = (tj != tiB);
        ckB[j] = c0;
        ((float*)v4sB)[j] = n0 ? (c0 + fabsf(cpB - cpj)) : -1e30f;
        if (!n0 && j != iB) pkB[atomicAdd(&pcB, 1u)] = j;
        nc += (n0 ? 1 : 0) << 16;
    }
    // wave-shuffle reduce negcounts, then 8-slot LDS
#pragma unroll
    for (int m = 1; m <= 32; m <<= 1) nc += __shfl_xor(nc, m);
    if ((tid & 63) == 0) wi[tid >> 6] = nc;
    __syncthreads();   // covers wi AND the setup writes (ck/v4s/pk/pc)
    int negpack = 0;
#pragma unroll
    for (int q = 0; q < 8; q++) negpack += wi[q];
    const int negA = negpack & 0xffff;
    const int negB = negpack >> 16;
    const unsigned int nposA = pcA, nposB = pcB;

    const int kl = tid & 31, jc = tid >> 5;
    const float denA = (float)(negA > 1 ? negA : 1);
    const float denB = (float)(negB > 1 ? negB : 1);
    float contrib = 0.0f;
    int nzc = 0;

    {   // anchor A
        float4 vj[8];
#pragma unroll
        for (int t = 0; t < 8; t++) vj[t] = v4sA[jc * 8 + t];
        for (unsigned int p = kl; p < nposA; p += 32) {
            const float ckp = ckA[pkA[p]];
            float s0 = 0.0f, s1 = 0.0f;
#pragma unroll
            for (int t = 0; t < 8; t++) {
                float4 wv = vj[t];
                s0 += fmaxf(wv.x - ckp, 0.0f) + fmaxf(wv.y - ckp, 0.0f);
                s1 += fmaxf(wv.z - ckp, 0.0f) + fmaxf(wv.w - ckp, 0.0f);
            }
            spart[p * 17 + jc] = s0 + s1;
        }
        __syncthreads();
        for (unsigned int p = tid; p < nposA; p += 512) {
            float s0 = 0.0f;
#pragma unroll
            for (int q = 0; q < 16; q++) s0 += spart[p * 17 + q];
            contrib += s0 / denA;
            if (s0 != 0.0f) nzc++;
        }
        __syncthreads();
    }
    {   // anchor B
        float4 vj[8];
#pragma unroll
        for (int t = 0; t < 8; t++) vj[t] = v4sB[jc * 8 + t];
        for (unsigned int p = kl; p < nposB; p += 32) {
            const float ckp = ckB[pkB[p]];
            float s0 = 0.0f, s1 = 0.0f;
#pragma unroll
            for (int t = 0; t < 8; t++) {
                float4 wv = vj[t];
                s0 += fmaxf(wv.x - ckp, 0.0f) + fmaxf(wv.y - ckp, 0.0f);
                s1 += fmaxf(wv.z - ckp, 0.0f) + fmaxf(wv.w - ckp, 0.0f);
            }
            spart[p * 17 + jc] = s0 + s1;
        }
        __syncthreads();
        for (unsigned int p = tid; p < nposB; p += 512) {
            float s0 = 0.0f;
#pragma unroll
            for (int q = 0; q < 16; q++) s0 += spart[p * 17 + q];
            contrib += s0 / denB;
            if (s0 != 0.0f) nzc++;
        }
    }

    // ---- shuffle block reduction of (contrib, nzc) ----
#pragma unroll
    for (int m = 1; m <= 32; m <<= 1) {
        contrib += __shfl_xor(contrib, m);
        nzc     += __shfl_xor(nzc, m);
    }
    __syncthreads();   // protect wf/wi reuse
    if ((tid & 63) == 0) { wf[tid >> 6] = contrib; wi[tid >> 6] = nzc; }
    __syncthreads();

    if (tid == 0) {
        float s = 0.0f; int nn = 0;
#pragma unroll
        for (int q = 0; q < 8; q++) { s += wf[q]; nn += wi[q]; }
        psum[b] = s;           // distinct cacheline per block, plain store
        pnz[b]  = nn;
        __threadfence();       // release partials device-scope
        unsigned int t = atomicAdd(ticket, 1u);   // single fire-and-forget RMW
        last_flag = (t == (unsigned int)(gridDim.x - 1)) ? 1u : 0u;
    }
    __syncthreads();

    if (last_flag) {
        __threadfence();       // acquire before reading remote partials
        float v = 0.0f; int n = 0;
        if (tid < NBLK) {
            v = __hip_atomic_load(&psum[tid], __ATOMIC_RELAXED, __HIP_MEMORY_SCOPE_AGENT);
            n = __hip_atomic_load(&pnz[tid],  __ATOMIC_RELAXED, __HIP_MEMORY_SCOPE_AGENT);
        }
#pragma unroll
        for (int m = 1; m <= 32; m <<= 1) { v += __shfl_xor(v, m); n += __shfl_xor(n, m); }
        __syncthreads();       // wf/wi reuse
        if ((tid & 63) == 0) { wf[tid >> 6] = v; wi[tid >> 6] = n; }
        __syncthreads();
        if (tid == 0) {
            float s = 0.0f; int nn = 0;
#pragma unroll
            for (int q = 0; q < 8; q++) { s += wf[q]; nn += wi[q]; }
            out[0] = s / (float)(nn > 1 ? nn : 1);
        }
    }
}

extern "C" void kernel_launch(void* const* d_in, const int* in_sizes, int n_in,
                              void* d_out, int out_size, void* d_ws, size_t ws_size,
                              hipStream_t stream) {
    const float* pred   = (const float*)d_in[0];
    const float* draw   = (const float*)d_in[1];
    const int*   target = (const int*)d_in[2];
    float* out = (float*)d_out;

    float* ws   = (float*)d_ws;
    float* dots = ws;                             // 512*512 floats (1 MB)
    float* dg   = ws + NS * NS;                   // 512 floats
    float* psum = dg + NS;                        // 256 floats
    int*   pnz  = (int*)(psum + NBLK);            // 256 ints
    unsigned int* ticket = (unsigned int*)(pnz + NBLK);

    hipLaunchKernelGGL(k_dots, dim3(32, 8), dim3(512), 0, stream, pred, dots, dg, ticket);
    hipLaunchKernelGGL(k_loss, dim3(NBLK), dim3(512), 0, stream,
                       dots, dg, target, draw, psum, pnz, ticket, out);
}

// Round 16
// 84.266 us; speedup vs baseline: 1.0330x; 1.0330x over previous
//
#include <hip/hip_runtime.h>
#include <math.h>

#define NS 512
#define DE 512
#define NCL 5
#define NBLK 256

// ws layout: psum[256] f32 | pnz[256] i32 | ticket u32   (zeroed by memset node)

// ---------------------------------------------------------------------------
// Fused kernel (R13 body verbatim). Block b: anchors iA=b, iB=b+256.
// Phase 1: coalesced triple-dot. Phase 2: block-local loss.
// Ending (new): fence-free — uncontended per-block atomicAdd partials
// (coherence-point ops, no L2-writeback fence needed), waitcnt-ordered
// ticket RMW, last block reduces partials via agent-scope atomic loads.
// ---------------------------------------------------------------------------
__global__ __launch_bounds__(512) void k_all(const float* __restrict__ pred,
                                             const int* __restrict__ target,
                                             const float* __restrict__ draw,
                                             float* __restrict__ psum,
                                             int* __restrict__ pnz,
                                             unsigned int* __restrict__ ticket,
                                             float* __restrict__ out) {
    const int b = blockIdx.x;
    const int tid = threadIdx.x;
    const int iA = b, iB = b + 256;

    __shared__ float  rn_s[NS];
    __shared__ float  ckA[NS], ckB[NS];        // raw dots, then cos in place
    __shared__ float4 v4sA[NS / 4], v4sB[NS / 4];
    __shared__ int    pkA[NS], pkB[NS];
    __shared__ float  spart[NS * 17];          // 34 KB
    __shared__ float  redf[512];
    __shared__ int    redi[512];
    __shared__ unsigned int pcA, pcB, last_flag;

    if (tid == 0) { pcA = 0u; pcB = 0u; }

    // ================= phase 1: coalesced triple dots =================
    const int w = tid >> 6, lane = tid & 63;
    const int g = lane >> 4, s = lane & 15;

    const float4* pA = (const float4*)&pred[(size_t)iA * DE];
    const float4* pB = (const float4*)&pred[(size_t)iB * DE];
    float4 fA[8], fB[8];
#pragma unroll
    for (int p = 0; p < 8; p++) { fA[p] = pA[p * 16 + s]; fB[p] = pB[p * 16 + s]; }

#pragma unroll 4
    for (int t = 0; t < 16; t++) {
        const int j = w * 64 + t * 4 + g;
        const float4* rj = (const float4*)&pred[(size_t)j * DE];
        float aA = 0.0f, aB = 0.0f, aS = 0.0f;
#pragma unroll
        for (int p = 0; p < 8; p++) {
            float4 x = rj[p * 16 + s];
            aA = fmaf(x.x, fA[p].x, aA); aA = fmaf(x.y, fA[p].y, aA);
            aA = fmaf(x.z, fA[p].z, aA); aA = fmaf(x.w, fA[p].w, aA);
            aB = fmaf(x.x, fB[p].x, aB); aB = fmaf(x.y, fB[p].y, aB);
            aB = fmaf(x.z, fB[p].z, aB); aB = fmaf(x.w, fB[p].w, aB);
            aS = fmaf(x.x, x.x, aS);     aS = fmaf(x.y, x.y, aS);
            aS = fmaf(x.z, x.z, aS);     aS = fmaf(x.w, x.w, aS);
        }
#pragma unroll
        for (int m = 1; m <= 8; m <<= 1) {
            aA += __shfl_xor(aA, m);
            aB += __shfl_xor(aB, m);
            aS += __shfl_xor(aS, m);
        }
        if (s == 0) {
            ckA[j] = aA;
            ckB[j] = aB;
            rn_s[j] = 1.0f / fmaxf(sqrtf(aS), 1e-8f);
        }
    }

    // ordinal class positions
    float cp[NCL];
    cp[0] = 0.0f;
#pragma unroll
    for (int c = 0; c < NCL - 1; c++) cp[c + 1] = cp[c] + log1pf(expf(draw[c]));
    const int tiA = target[iA], tiB = target[iB];
    const float cpA = cp[tiA], cpB = cp[tiB];
    const int j = tid;
    const int tj = target[j];
    const float cpj = cp[tj];
    __syncthreads();

    // ================= phase 2: loss setup =================
    const float rniA = rn_s[iA], rniB = rn_s[iB], rnj = rn_s[j];
    {   // anchor A
        float c0 = ckA[j] * rniA * rnj;
        bool n0 = (tj != tiA);
        ckA[j] = c0;
        ((float*)v4sA)[j] = n0 ? (c0 + fabsf(cpA - cpj)) : -1e30f;
        if (!n0 && j != iA) pkA[atomicAdd(&pcA, 1u)] = j;
        redi[tid] = (n0 ? 1 : 0);
    }
    {   // anchor B (negcounts packed: A low 16, B high 16)
        float c0 = ckB[j] * rniB * rnj;
        bool n0 = (tj != tiB);
        ckB[j] = c0;
        ((float*)v4sB)[j] = n0 ? (c0 + fabsf(cpB - cpj)) : -1e30f;
        if (!n0 && j != iB) pkB[atomicAdd(&pcB, 1u)] = j;
        redi[tid] += (n0 ? 1 : 0) << 16;
    }
    __syncthreads();
    for (int s2 = 256; s2 > 0; s2 >>= 1) {
        if (tid < s2) redi[tid] += redi[tid + s2];
        __syncthreads();
    }
    const int negA = redi[0] & 0xffff;
    const int negB = redi[0] >> 16;
    const unsigned int nposA = pcA, nposB = pcB;
    __syncthreads();

    // pass1 split: 32 k-lanes x 16 j-chunks (32 j's each, cached in VGPRs)
    const int kl = tid & 31, jc = tid >> 5;
    const float denA = (float)(negA > 1 ? negA : 1);
    const float denB = (float)(negB > 1 ? negB : 1);
    float contrib = 0.0f;
    int nzc = 0;

    {   // anchor A
        float4 vj[8];
#pragma unroll
        for (int t = 0; t < 8; t++) vj[t] = v4sA[jc * 8 + t];
        for (unsigned int p = kl; p < nposA; p += 32) {
            const float ckp = ckA[pkA[p]];
            float s0 = 0.0f, s1 = 0.0f;
#pragma unroll
            for (int t = 0; t < 8; t++) {
                float4 wv = vj[t];
                s0 += fmaxf(wv.x - ckp, 0.0f) + fmaxf(wv.y - ckp, 0.0f);
                s1 += fmaxf(wv.z - ckp, 0.0f) + fmaxf(wv.w - ckp, 0.0f);
            }
            spart[p * 17 + jc] = s0 + s1;
        }
        __syncthreads();
        for (unsigned int p = tid; p < nposA; p += 512) {
            float s0 = 0.0f;
#pragma unroll
            for (int q = 0; q < 16; q++) s0 += spart[p * 17 + q];
            contrib += s0 / denA;
            if (s0 != 0.0f) nzc++;
        }
        __syncthreads();
    }
    {   // anchor B
        float4 vj[8];
#pragma unroll
        for (int t = 0; t < 8; t++) vj[t] = v4sB[jc * 8 + t];
        for (unsigned int p = kl; p < nposB; p += 32) {
            const float ckp = ckB[pkB[p]];
            float s0 = 0.0f, s1 = 0.0f;
#pragma unroll
            for (int t = 0; t < 8; t++) {
                float4 wv = vj[t];
                s0 += fmaxf(wv.x - ckp, 0.0f) + fmaxf(wv.y - ckp, 0.0f);
                s1 += fmaxf(wv.z - ckp, 0.0f) + fmaxf(wv.w - ckp, 0.0f);
            }
            spart[p * 17 + jc] = s0 + s1;
        }
        __syncthreads();
        for (unsigned int p = tid; p < nposB; p += 512) {
            float s0 = 0.0f;
#pragma unroll
            for (int q = 0; q < 16; q++) s0 += spart[p * 17 + q];
            contrib += s0 / denB;
            if (s0 != 0.0f) nzc++;
        }
    }

    // ---- block reduction ----
    redf[tid] = contrib;
    redi[tid] = nzc;
    __syncthreads();
    for (int s2 = 256; s2 > 0; s2 >>= 1) {
        if (tid < s2) { redf[tid] += redf[tid + s2]; redi[tid] += redi[tid + s2]; }
        __syncthreads();
    }

    // ---- fence-free finalize ----
    if (tid == 0) {
        // uncontended coherence-point adds (distinct line per block)
        float oldf = atomicAdd(&psum[b], redf[0]);
        int   oldi = atomicAdd(&pnz[b],  redi[0]);
        __builtin_amdgcn_s_waitcnt(0);           // data atomics complete...
        if (__float_as_uint(oldf) + (unsigned int)oldi == 0xFFFFFFFFu)
            pnz[b] = 0;                          // never true (olds are 0); keeps returns live
        unsigned int t = atomicAdd(ticket, 1u);  // ...before the ticket RMW
        last_flag = (t == (unsigned int)(NBLK - 1)) ? 1u : 0u;
    }
    __syncthreads();

    if (last_flag) {
        float v = 0.0f; int n = 0;
        if (tid < NBLK) {
            v = __hip_atomic_load(&psum[tid], __ATOMIC_RELAXED, __HIP_MEMORY_SCOPE_AGENT);
            n = __hip_atomic_load(&pnz[tid],  __ATOMIC_RELAXED, __HIP_MEMORY_SCOPE_AGENT);
        }
        redf[tid] = v;
        redi[tid] = n;
        __syncthreads();
        for (int s2 = 256; s2 > 0; s2 >>= 1) {
            if (tid < s2) { redf[tid] += redf[tid + s2]; redi[tid] += redi[tid + s2]; }
            __syncthreads();
        }
        if (tid == 0) {
            int nn = redi[0];
            out[0] = redf[0] / (float)(nn > 1 ? nn : 1);
        }
    }
}

extern "C" void kernel_launch(void* const* d_in, const int* in_sizes, int n_in,
                              void* d_out, int out_size, void* d_ws, size_t ws_size,
                              hipStream_t stream) {
    const float* pred   = (const float*)d_in[0];
    const float* draw   = (const float*)d_in[1];
    const int*   target = (const int*)d_in[2];
    float* out = (float*)d_out;

    float* psum = (float*)d_ws;                       // 256 floats
    int*   pnz  = (int*)(psum + NBLK);                // 256 ints
    unsigned int* ticket = (unsigned int*)(pnz + NBLK);

    hipMemsetAsync(d_ws, 0, (2 * NBLK + 1) * sizeof(float), stream);
    hipLaunchKernelGGL(k_all, dim3(NBLK), dim3(512), 0, stream,
                       pred, target, draw, psum, pnz, ticket, out);
}

// Round 17
// 76.666 us; speedup vs baseline: 1.1354x; 1.0991x over previous
//
#include <hip/hip_runtime.h>
#include <math.h>

#define NS 512
#define DE 512
#define NCL 5
#define NBLK 256

// ws layout: psum[256] | pnz[256]  (no ctrl, no memset — fully rewritten each launch)

// ---------------------------------------------------------------------------
// Fused kernel (R13 structure). Block b: anchors iA=b, iB=b+256.
// Phase 1: coalesced triple-dot with SOFTWARE-PIPELINED loads (double-
// buffered x registers: t+1's 8 loads issued before t's FMA block).
// Phase 2: block-local loss. Ending: plain partial stores (R13-proven).
// ---------------------------------------------------------------------------
__global__ __launch_bounds__(512) void k_all(const float* __restrict__ pred,
                                             const int* __restrict__ target,
                                             const float* __restrict__ draw,
                                             float* __restrict__ psum,
                                             int* __restrict__ pnz) {
    const int b = blockIdx.x;
    const int tid = threadIdx.x;
    const int iA = b, iB = b + 256;

    __shared__ float  rn_s[NS];
    __shared__ float  ckA[NS], ckB[NS];        // raw dots, then cos in place
    __shared__ float4 v4sA[NS / 4], v4sB[NS / 4];
    __shared__ int    pkA[NS], pkB[NS];
    __shared__ float  spart[NS * 17];          // 34 KB
    __shared__ float  redf[512];
    __shared__ int    redi[512];
    __shared__ unsigned int pcA, pcB;

    if (tid == 0) { pcA = 0u; pcB = 0u; }

    // ================= phase 1: pipelined coalesced triple dots ============
    const int w = tid >> 6, lane = tid & 63;
    const int g = lane >> 4, s = lane & 15;

    const float4* pA = (const float4*)&pred[(size_t)iA * DE];
    const float4* pB = (const float4*)&pred[(size_t)iB * DE];
    float4 fA[8], fB[8];
#pragma unroll
    for (int p = 0; p < 8; p++) { fA[p] = pA[p * 16 + s]; fB[p] = pB[p * 16 + s]; }

    const float4* p4 = (const float4*)pred;
    const float4* rj0 = p4 + (size_t)(w * 64 + g) * (DE / 4);   // row for t=0
    float4 xc[8];
#pragma unroll
    for (int p = 0; p < 8; p++) xc[p] = rj0[p * 16 + s];

#pragma unroll
    for (int t = 0; t < 16; t++) {
        float4 xn[8];
        if (t < 15) {
            const float4* rjn = rj0 + (size_t)(t + 1) * 4 * (DE / 4);
#pragma unroll
            for (int p = 0; p < 8; p++) xn[p] = rjn[p * 16 + s];  // in flight over FMAs
        }
        const int j = w * 64 + t * 4 + g;
        float aA = 0.0f, aB = 0.0f, aS = 0.0f;
#pragma unroll
        for (int p = 0; p < 8; p++) {
            float4 x = xc[p];
            aA = fmaf(x.x, fA[p].x, aA); aA = fmaf(x.y, fA[p].y, aA);
            aA = fmaf(x.z, fA[p].z, aA); aA = fmaf(x.w, fA[p].w, aA);
            aB = fmaf(x.x, fB[p].x, aB); aB = fmaf(x.y, fB[p].y, aB);
            aB = fmaf(x.z, fB[p].z, aB); aB = fmaf(x.w, fB[p].w, aB);
            aS = fmaf(x.x, x.x, aS);     aS = fmaf(x.y, x.y, aS);
            aS = fmaf(x.z, x.z, aS);     aS = fmaf(x.w, x.w, aS);
        }
#pragma unroll
        for (int m = 1; m <= 8; m <<= 1) {
            aA += __shfl_xor(aA, m);
            aB += __shfl_xor(aB, m);
            aS += __shfl_xor(aS, m);
        }
        if (s == 0) {
            ckA[j] = aA;
            ckB[j] = aB;
            rn_s[j] = 1.0f / fmaxf(sqrtf(aS), 1e-8f);
        }
#pragma unroll
        for (int p = 0; p < 8; p++) xc[p] = xn[p];
    }

    // ordinal class positions
    float cp[NCL];
    cp[0] = 0.0f;
#pragma unroll
    for (int c = 0; c < NCL - 1; c++) cp[c + 1] = cp[c] + log1pf(expf(draw[c]));
    const int tiA = target[iA], tiB = target[iB];
    const float cpA = cp[tiA], cpB = cp[tiB];
    const int j = tid;
    const int tj = target[j];
    const float cpj = cp[tj];
    __syncthreads();

    // ================= phase 2: loss setup =================
    const float rniA = rn_s[iA], rniB = rn_s[iB], rnj = rn_s[j];
    {   // anchor A
        float c0 = ckA[j] * rniA * rnj;
        bool n0 = (tj != tiA);
        ckA[j] = c0;
        ((float*)v4sA)[j] = n0 ? (c0 + fabsf(cpA - cpj)) : -1e30f;
        if (!n0 && j != iA) pkA[atomicAdd(&pcA, 1u)] = j;
        redi[tid] = (n0 ? 1 : 0);
    }
    {   // anchor B (negcounts packed: A low 16, B high 16)
        float c0 = ckB[j] * rniB * rnj;
        bool n0 = (tj != tiB);
        ckB[j] = c0;
        ((float*)v4sB)[j] = n0 ? (c0 + fabsf(cpB - cpj)) : -1e30f;
        if (!n0 && j != iB) pkB[atomicAdd(&pcB, 1u)] = j;
        redi[tid] += (n0 ? 1 : 0) << 16;
    }
    __syncthreads();
    for (int s2 = 256; s2 > 0; s2 >>= 1) {
        if (tid < s2) redi[tid] += redi[tid + s2];
        __syncthreads();
    }
    const int negA = redi[0] & 0xffff;
    const int negB = redi[0] >> 16;
    const unsigned int nposA = pcA, nposB = pcB;
    __syncthreads();

    // pass1 split: 32 k-lanes x 16 j-chunks (32 j's each, cached in VGPRs)
    const int kl = tid & 31, jc = tid >> 5;
    const float denA = (float)(negA > 1 ? negA : 1);
    const float denB = (float)(negB > 1 ? negB : 1);
    float contrib = 0.0f;
    int nzc = 0;

    {   // anchor A
        float4 vj[8];
#pragma unroll
        for (int t = 0; t < 8; t++) vj[t] = v4sA[jc * 8 + t];
        for (unsigned int p = kl; p < nposA; p += 32) {
            const float ckp = ckA[pkA[p]];
            float s0 = 0.0f, s1 = 0.0f;
#pragma unroll
            for (int t = 0; t < 8; t++) {
                float4 wv = vj[t];
                s0 += fmaxf(wv.x - ckp, 0.0f) + fmaxf(wv.y - ckp, 0.0f);
                s1 += fmaxf(wv.z - ckp, 0.0f) + fmaxf(wv.w - ckp, 0.0f);
            }
            spart[p * 17 + jc] = s0 + s1;
        }
        __syncthreads();
        for (unsigned int p = tid; p < nposA; p += 512) {
            float s0 = 0.0f;
#pragma unroll
            for (int q = 0; q < 16; q++) s0 += spart[p * 17 + q];
            contrib += s0 / denA;
            if (s0 != 0.0f) nzc++;
        }
        __syncthreads();
    }
    {   // anchor B
        float4 vj[8];
#pragma unroll
        for (int t = 0; t < 8; t++) vj[t] = v4sB[jc * 8 + t];
        for (unsigned int p = kl; p < nposB; p += 32) {
            const float ckp = ckB[pkB[p]];
            float s0 = 0.0f, s1 = 0.0f;
#pragma unroll
            for (int t = 0; t < 8; t++) {
                float4 wv = vj[t];
                s0 += fmaxf(wv.x - ckp, 0.0f) + fmaxf(wv.y - ckp, 0.0f);
                s1 += fmaxf(wv.z - ckp, 0.0f) + fmaxf(wv.w - ckp, 0.0f);
            }
            spart[p * 17 + jc] = s0 + s1;
        }
        __syncthreads();
        for (unsigned int p = tid; p < nposB; p += 512) {
            float s0 = 0.0f;
#pragma unroll
            for (int q = 0; q < 16; q++) s0 += spart[p * 17 + q];
            contrib += s0 / denB;
            if (s0 != 0.0f) nzc++;
        }
    }

    // ---- block reduction, partials to distinct cachelines (NO atomics) ----
    redf[tid] = contrib;
    redi[tid] = nzc;
    __syncthreads();
    for (int s2 = 256; s2 > 0; s2 >>= 1) {
        if (tid < s2) { redf[tid] += redf[tid + s2]; redi[tid] += redi[tid + s2]; }
        __syncthreads();
    }
    if (tid == 0) {
        psum[b] = redf[0];
        pnz[b]  = redi[0];
    }
}

// ---------------------------------------------------------------------------
// Final: reduce 256 partials, out = sum / max(nz, 1)
// ---------------------------------------------------------------------------
__global__ __launch_bounds__(256) void k_final(const float* __restrict__ psum,
                                               const int* __restrict__ pnz,
                                               float* __restrict__ out) {
    const int tid = threadIdx.x;
    __shared__ float rf[256];
    __shared__ int   ri[256];
    rf[tid] = psum[tid];
    ri[tid] = pnz[tid];
    __syncthreads();
    for (int s = 128; s > 0; s >>= 1) {
        if (tid < s) { rf[tid] += rf[tid + s]; ri[tid] += ri[tid + s]; }
        __syncthreads();
    }
    if (tid == 0) {
        int n = ri[0];
        out[0] = rf[0] / (float)(n > 1 ? n : 1);
    }
}

extern "C" void kernel_launch(void* const* d_in, const int* in_sizes, int n_in,
                              void* d_out, int out_size, void* d_ws, size_t ws_size,
                              hipStream_t stream) {
    const float* pred   = (const float*)d_in[0];
    const float* draw   = (const float*)d_in[1];
    const int*   target = (const int*)d_in[2];
    float* out = (float*)d_out;

    float* psum = (float*)d_ws;                  // 256 floats
    int*   pnz  = (int*)(psum + NBLK);           // 256 ints

    hipLaunchKernelGGL(k_all, dim3(NBLK), dim3(512), 0, stream,
                       pred, target, draw, psum, pnz);
    hipLaunchKernelGGL(k_final, dim3(1), dim3(256), 0, stream, psum, pnz, out);
}

// Round 18
// 75.883 us; speedup vs baseline: 1.1471x; 1.0103x over previous
//
#include <hip/hip_runtime.h>
#include <math.h>

#define NS 512
#define DE 512
#define NCL 5
#define NBLK 256

// ws layout: psum[256] | pnz[256]  (no ctrl, no memset — fully rewritten each launch)

// ---------------------------------------------------------------------------
// Fused kernel (R17 structure). Block b: anchors iA=b, iB=b+256.
// Phase 1: coalesced triple-dot, 2-DEEP software pipeline (x0/x1/xn rotate).
// Phase 2: block-local loss, shuffle reductions (no LDS trees).
// Ending: plain partial stores to distinct lines (R13-proven) + k_final.
// ---------------------------------------------------------------------------
__global__ __launch_bounds__(512, 2) void k_all(const float* __restrict__ pred,
                                                const int* __restrict__ target,
                                                const float* __restrict__ draw,
                                                float* __restrict__ psum,
                                                int* __restrict__ pnz) {
    const int b = blockIdx.x;
    const int tid = threadIdx.x;
    const int iA = b, iB = b + 256;

    __shared__ float  rn_s[NS];
    __shared__ float  ckA[NS], ckB[NS];        // raw dots, then cos in place
    __shared__ float4 v4sA[NS / 4], v4sB[NS / 4];
    __shared__ int    pkA[NS], pkB[NS];
    __shared__ float  spart[NS * 17];          // 34 KB
    __shared__ float  wf[8];
    __shared__ int    wi[8];
    __shared__ unsigned int pcA, pcB;

    if (tid == 0) { pcA = 0u; pcB = 0u; }

    // ================= phase 1: 2-deep pipelined triple dots ============
    const int w = tid >> 6, lane = tid & 63;
    const int g = lane >> 4, s = lane & 15;

    const float4* pA = (const float4*)&pred[(size_t)iA * DE];
    const float4* pB = (const float4*)&pred[(size_t)iB * DE];
    float4 fA[8], fB[8];
#pragma unroll
    for (int p = 0; p < 8; p++) { fA[p] = pA[p * 16 + s]; fB[p] = pB[p * 16 + s]; }

    const float4* p4 = (const float4*)pred;
    const float4* rj0 = p4 + (size_t)(w * 64 + g) * (DE / 4);   // row for t=0
    const int rstep = 4 * (DE / 4);                              // +4 rows
    float4 x0[8], x1[8];
#pragma unroll
    for (int p = 0; p < 8; p++) x0[p] = rj0[p * 16 + s];
#pragma unroll
    for (int p = 0; p < 8; p++) x1[p] = rj0[rstep + p * 16 + s];

#pragma unroll
    for (int t = 0; t < 16; t++) {
        float4 xn[8];
        if (t < 14) {
            const float4* rjn = rj0 + (size_t)(t + 2) * rstep;
#pragma unroll
            for (int p = 0; p < 8; p++) xn[p] = rjn[p * 16 + s];  // in flight 2 steps
        }
        const int j = w * 64 + t * 4 + g;
        float aA = 0.0f, aB = 0.0f, aS = 0.0f;
#pragma unroll
        for (int p = 0; p < 8; p++) {
            float4 x = x0[p];
            aA = fmaf(x.x, fA[p].x, aA); aA = fmaf(x.y, fA[p].y, aA);
            aA = fmaf(x.z, fA[p].z, aA); aA = fmaf(x.w, fA[p].w, aA);
            aB = fmaf(x.x, fB[p].x, aB); aB = fmaf(x.y, fB[p].y, aB);
            aB = fmaf(x.z, fB[p].z, aB); aB = fmaf(x.w, fB[p].w, aB);
            aS = fmaf(x.x, x.x, aS);     aS = fmaf(x.y, x.y, aS);
            aS = fmaf(x.z, x.z, aS);     aS = fmaf(x.w, x.w, aS);
        }
#pragma unroll
        for (int m = 1; m <= 8; m <<= 1) {
            aA += __shfl_xor(aA, m);
            aB += __shfl_xor(aB, m);
            aS += __shfl_xor(aS, m);
        }
        if (s == 0) {
            ckA[j] = aA;
            ckB[j] = aB;
            rn_s[j] = 1.0f / fmaxf(sqrtf(aS), 1e-8f);
        }
#pragma unroll
        for (int p = 0; p < 8; p++) { x0[p] = x1[p]; x1[p] = xn[p]; }
    }

    // ordinal class positions
    float cp[NCL];
    cp[0] = 0.0f;
#pragma unroll
    for (int c = 0; c < NCL - 1; c++) cp[c + 1] = cp[c] + log1pf(expf(draw[c]));
    const int tiA = target[iA], tiB = target[iB];
    const float cpA = cp[tiA], cpB = cp[tiB];
    const int j = tid;
    const int tj = target[j];
    const float cpj = cp[tj];
    __syncthreads();

    // ================= phase 2: loss setup =================
    const float rniA = rn_s[iA], rniB = rn_s[iB], rnj = rn_s[j];
    int nc;
    {   // anchor A
        float c0 = ckA[j] * rniA * rnj;
        bool n0 = (tj != tiA);
        ckA[j] = c0;
        ((float*)v4sA)[j] = n0 ? (c0 + fabsf(cpA - cpj)) : -1e30f;
        if (!n0 && j != iA) pkA[atomicAdd(&pcA, 1u)] = j;
        nc = (n0 ? 1 : 0);
    }
    {   // anchor B (negcounts packed: A low 16, B high 16)
        float c0 = ckB[j] * rniB * rnj;
        bool n0 = (tj != tiB);
        ckB[j] = c0;
        ((float*)v4sB)[j] = n0 ? (c0 + fabsf(cpB - cpj)) : -1e30f;
        if (!n0 && j != iB) pkB[atomicAdd(&pcB, 1u)] = j;
        nc += (n0 ? 1 : 0) << 16;
    }
    // shuffle reduce negcounts (64-lane wave), leaders -> wi[8]
#pragma unroll
    for (int m = 1; m <= 32; m <<= 1) nc += __shfl_xor(nc, m);
    if ((tid & 63) == 0) wi[tid >> 6] = nc;
    __syncthreads();   // covers wi AND the setup writes (ck/v4s/pk/pc)
    int negpack = 0;
#pragma unroll
    for (int q = 0; q < 8; q++) negpack += wi[q];
    const int negA = negpack & 0xffff;
    const int negB = negpack >> 16;
    const unsigned int nposA = pcA, nposB = pcB;

    // pass1 split: 32 k-lanes x 16 j-chunks (32 j's each, cached in VGPRs)
    const int kl = tid & 31, jc = tid >> 5;
    const float denA = (float)(negA > 1 ? negA : 1);
    const float denB = (float)(negB > 1 ? negB : 1);
    float contrib = 0.0f;
    int nzc = 0;

    {   // anchor A
        float4 vj[8];
#pragma unroll
        for (int t = 0; t < 8; t++) vj[t] = v4sA[jc * 8 + t];
        for (unsigned int p = kl; p < nposA; p += 32) {
            const float ckp = ckA[pkA[p]];
            float s0 = 0.0f, s1 = 0.0f;
#pragma unroll
            for (int t = 0; t < 8; t++) {
                float4 wv = vj[t];
                s0 += fmaxf(wv.x - ckp, 0.0f) + fmaxf(wv.y - ckp, 0.0f);
                s1 += fmaxf(wv.z - ckp, 0.0f) + fmaxf(wv.w - ckp, 0.0f);
            }
            spart[p * 17 + jc] = s0 + s1;
        }
        __syncthreads();
        for (unsigned int p = tid; p < nposA; p += 512) {
            float s0 = 0.0f;
#pragma unroll
            for (int q = 0; q < 16; q++) s0 += spart[p * 17 + q];
            contrib += s0 / denA;
            if (s0 != 0.0f) nzc++;
        }
        __syncthreads();
    }
    {   // anchor B
        float4 vj[8];
#pragma unroll
        for (int t = 0; t < 8; t++) vj[t] = v4sB[jc * 8 + t];
        for (unsigned int p = kl; p < nposB; p += 32) {
            const float ckp = ckB[pkB[p]];
            float s0 = 0.0f, s1 = 0.0f;
#pragma unroll
            for (int t = 0; t < 8; t++) {
                float4 wv = vj[t];
                s0 += fmaxf(wv.x - ckp, 0.0f) + fmaxf(wv.y - ckp, 0.0f);
                s1 += fmaxf(wv.z - ckp, 0.0f) + fmaxf(wv.w - ckp, 0.0f);
            }
            spart[p * 17 + jc] = s0 + s1;
        }
        __syncthreads();
        for (unsigned int p = tid; p < nposB; p += 512) {
            float s0 = 0.0f;
#pragma unroll
            for (int q = 0; q < 16; q++) s0 += spart[p * 17 + q];
            contrib += s0 / denB;
            if (s0 != 0.0f) nzc++;
        }
    }

    // ---- shuffle block reduction, partials to distinct cachelines ----
#pragma unroll
    for (int m = 1; m <= 32; m <<= 1) {
        contrib += __shfl_xor(contrib, m);
        nzc     += __shfl_xor(nzc, m);
    }
    __syncthreads();   // protect wf/wi reuse
    if ((tid & 63) == 0) { wf[tid >> 6] = contrib; wi[tid >> 6] = nzc; }
    __syncthreads();
    if (tid == 0) {
        float sfin = 0.0f; int nfin = 0;
#pragma unroll
        for (int q = 0; q < 8; q++) { sfin += wf[q]; nfin += wi[q]; }
        psum[b] = sfin;
        pnz[b]  = nfin;
    }
}

// ---------------------------------------------------------------------------
// Final: reduce 256 partials, out = sum / max(nz, 1)
// ---------------------------------------------------------------------------
__global__ __launch_bounds__(256) void k_final(const float* __restrict__ psum,
                                               const int* __restrict__ pnz,
                                               float* __restrict__ out) {
    const int tid = threadIdx.x;
    __shared__ float rf[256];
    __shared__ int   ri[256];
    rf[tid] = psum[tid];
    ri[tid] = pnz[tid];
    __syncthreads();
    for (int s = 128; s > 0; s >>= 1) {
        if (tid < s) { rf[tid] += rf[tid + s]; ri[tid] += ri[tid + s]; }
        __syncthreads();
    }
    if (tid == 0) {
        int n = ri[0];
        out[0] = rf[0] / (float)(n > 1 ? n : 1);
    }
}

extern "C" void kernel_launch(void* const* d_in, const int* in_sizes, int n_in,
                              void* d_out, int out_size, void* d_ws, size_t ws_size,
                              hipStream_t stream) {
    const float* pred   = (const float*)d_in[0];
    const float* draw   = (const float*)d_in[1];
    const int*   target = (const int*)d_in[2];
    float* out = (float*)d_out;

    float* psum = (float*)d_ws;                  // 256 floats
    int*   pnz  = (int*)(psum + NBLK);           // 256 ints

    hipLaunchKernelGGL(k_all, dim3(NBLK), dim3(512), 0, stream,
                       pred, target, draw, psum, pnz);
    hipLaunchKernelGGL(k_final, dim3(1), dim3(256), 0, stream, psum, pnz, out);
}